// Round 1
// baseline (1270.345 us; speedup 1.0000x reference)
//
#include <hip/hip_runtime.h>
#include <math.h>

#define N_NODES 20000
#define N_EDGES 320000

// f layout  (ws):  f[n*256 + u]            = f0[u]
//                  f[n*256 + 64 + 64*m+u]  = f1[u][m]   (SoA by component)
// acc layout (ws): acc[n*512 + c]              c<128 : s_mid channel c
//                  acc[n*512 + 128 + m*128+c]        : v_mid[c][m]
// out layout:      out[n*256 + u]  (scalars) ; out[n*256 + 64 + u*3 + m] (vectors)

__device__ __forceinline__ float silu_f(float x) {
    return x / (1.0f + expf(-x));
}

__global__ __launch_bounds__(256) void k_node_in(
    const float* __restrict__ ni, const float* __restrict__ attr,
    const float* __restrict__ deg,
    const float* __restrict__ Wli0, const float* __restrict__ Wli1,
    const float* __restrict__ Wlm0, const float* __restrict__ Wlm1,
    float* __restrict__ f, float* __restrict__ out)
{
    __shared__ float raw[4][256];
    const int wave = threadIdx.x >> 6;
    const int lane = threadIdx.x & 63;
    const int n = blockIdx.x * 4 + wave;

    const float* row = ni + (size_t)n * 256;
    raw[wave][lane      ] = row[lane      ];
    raw[wave][lane + 64 ] = row[lane + 64 ];
    raw[wave][lane + 128] = row[lane + 128];
    raw[wave][lane + 192] = row[lane + 192];
    __syncthreads();

    float f0 = 0.f, m0 = 0.f;
    float f1x = 0.f, f1y = 0.f, f1z = 0.f;
    float m1x = 0.f, m1y = 0.f, m1z = 0.f;
    #pragma unroll 4
    for (int t = 0; t < 64; ++t) {
        float xs  = raw[wave][t];
        float xv0 = raw[wave][64 + t*3    ];
        float xv1 = raw[wave][64 + t*3 + 1];
        float xv2 = raw[wave][64 + t*3 + 2];
        float a0 = Wli0[t*64 + lane];
        float a1 = Wli1[t*64 + lane];
        float b0 = Wlm0[t*64 + lane];
        float b1 = Wlm1[t*64 + lane];
        f0  += xs  * a0;   m0  += xs  * b0;
        f1x += xv0 * a1;   f1y += xv1 * a1;   f1z += xv2 * a1;
        m1x += xv0 * b1;   m1y += xv1 * b1;   m1z += xv2 * b1;
    }

    const float a   = attr[n] * 0.125f;               // attr / sqrt(64)
    const float dis = 1.0f / sqrtf(deg[n]);
    const float fa  = a * dis;

    float* fr = f + (size_t)n * 256;
    fr[lane      ] = f0  * fa;
    fr[64  + lane] = f1x * fa;
    fr[128 + lane] = f1y * fa;
    fr[192 + lane] = f1z * fa;

    const float c_s = 0.3826834323650898f;            // sin(pi/8)
    float* orow = out + (size_t)n * 256;
    orow[lane] = c_s * m0 * a;
    orow[64 + lane*3    ] = c_s * m1x * a;
    orow[64 + lane*3 + 1] = c_s * m1y * a;
    orow[64 + lane*3 + 2] = c_s * m1z * a;
}

__global__ __launch_bounds__(256) void k_edge(
    const float* __restrict__ eattr, const float* __restrict__ elen,
    const float* __restrict__ W1, const float* __restrict__ W2,
    const int* __restrict__ esrc, const int* __restrict__ edst,
    const float* __restrict__ f, float* __restrict__ acc)
{
    __shared__ float hsh[4][104];
    const int wave = threadIdx.x >> 6;
    const int lane = threadIdx.x & 63;
    const int e = blockIdx.x * 4 + wave;

    const float inv1 = 0.31622776601683794f;          // 1/sqrt(10)
    const float* el = elen + (size_t)e * 10;
    float elr[10];
    #pragma unroll
    for (int b = 0; b < 10; ++b) elr[b] = el[b];

    float a1 = 0.f;
    #pragma unroll
    for (int b = 0; b < 10; ++b) a1 += elr[b] * W1[b*100 + lane];
    hsh[wave][lane] = silu_f(a1 * inv1);
    if (lane < 36) {
        float a2 = 0.f;
        #pragma unroll
        for (int b = 0; b < 10; ++b) a2 += elr[b] * W1[b*100 + 64 + lane];
        hsh[wave][64 + lane] = silu_f(a2 * inv1);
    }
    __syncthreads();

    float wa = 0.f, wb = 0.f, wc = 0.f, wd = 0.f;
    #pragma unroll 4
    for (int j = 0; j < 100; ++j) {
        float hj = hsh[wave][j];
        const float* wr = W2 + j*256;
        wa += hj * wr[lane      ];
        wb += hj * wr[64  + lane];
        wc += hj * wr[128 + lane];
        wd += hj * wr[192 + lane];
    }
    wa *= 0.1f; wb *= 0.1f; wc *= 0.1f; wd *= 0.1f;   // /sqrt(100)

    const int src = esrc[e];
    const int dst = edst[e];
    const float y0  = eattr[e*4 + 0];
    const float y10 = eattr[e*4 + 1];
    const float y11 = eattr[e*4 + 2];
    const float y12 = eattr[e*4 + 3];

    const float* fr = f + (size_t)src * 256;
    const float g0  = fr[lane      ];
    const float g10 = fr[64  + lane];
    const float g11 = fr[128 + lane];
    const float g12 = fr[192 + lane];

    const float dotv = g10*y10 + g11*y11 + g12*y12;
    const float is3  = 0.5773502691896258f;           // 1/sqrt(3)

    float* ar = acc + (size_t)dst * 512;
    atomicAdd(ar + lane,                 wa * g0 * y0);
    atomicAdd(ar + 64 + lane,            wb * dotv * is3);
    atomicAdd(ar + 128 +   0 + lane,     wc * g0 * y10);
    atomicAdd(ar + 128 + 128 + lane,     wc * g0 * y11);
    atomicAdd(ar + 128 + 256 + lane,     wc * g0 * y12);
    atomicAdd(ar + 128 +   0 + 64 + lane, wd * g10 * y0);
    atomicAdd(ar + 128 + 128 + 64 + lane, wd * g11 * y0);
    atomicAdd(ar + 128 + 256 + 64 + lane, wd * g12 * y0);
}

__global__ __launch_bounds__(256) void k_node_out(
    const float* __restrict__ acc, const float* __restrict__ attr,
    const float* __restrict__ deg, const float* __restrict__ Wlo0,
    const float* __restrict__ Wlo1, float* __restrict__ out)
{
    __shared__ float sm[4][512];
    const int wave = threadIdx.x >> 6;
    const int lane = threadIdx.x & 63;
    const int n = blockIdx.x * 4 + wave;

    const float dis = 1.0f / sqrtf(deg[n]);
    const float* ar = acc + (size_t)n * 512;
    #pragma unroll
    for (int i = lane; i < 512; i += 64) sm[wave][i] = ar[i] * dis;
    __syncthreads();

    float o0 = 0.f, o1x = 0.f, o1y = 0.f, o1z = 0.f;
    #pragma unroll 4
    for (int c = 0; c < 128; ++c) {
        float w0 = Wlo0[c*64 + lane];
        float w1 = Wlo1[c*64 + lane];
        o0  += sm[wave][c]        * w0;
        o1x += sm[wave][128 + c]  * w1;
        o1y += sm[wave][256 + c]  * w1;
        o1z += sm[wave][384 + c]  * w1;
    }

    const float a   = attr[n] * 0.08838834764831845f; // attr / sqrt(128)
    const float c_x = 0.9238795325112867f;            // cos(pi/8)
    float* orow = out + (size_t)n * 256;
    orow[lane] += c_x * o0 * a;
    orow[64 + lane*3    ] += c_x * o1x * a;
    orow[64 + lane*3 + 1] += c_x * o1y * a;
    orow[64 + lane*3 + 2] += c_x * o1z * a;
}

extern "C" void kernel_launch(void* const* d_in, const int* in_sizes, int n_in,
                              void* d_out, int out_size, void* d_ws, size_t ws_size,
                              hipStream_t stream) {
    const float* ni    = (const float*)d_in[0];
    const float* attr  = (const float*)d_in[1];
    const float* deg   = (const float*)d_in[2];
    const float* eattr = (const float*)d_in[3];
    const float* elen  = (const float*)d_in[4];
    const float* Wli0  = (const float*)d_in[5];
    const float* Wli1  = (const float*)d_in[6];
    const float* Wlm0  = (const float*)d_in[7];
    const float* Wlm1  = (const float*)d_in[8];
    const float* Wm1   = (const float*)d_in[9];
    const float* Wm2   = (const float*)d_in[10];
    const float* Wlo0  = (const float*)d_in[11];
    const float* Wlo1  = (const float*)d_in[12];
    const int*   esrc  = (const int*)d_in[13];
    const int*   edst  = (const int*)d_in[14];

    float* out = (float*)d_out;
    float* f   = (float*)d_ws;                         // N_NODES*256 floats
    float* acc = f + (size_t)N_NODES * 256;            // N_NODES*512 floats

    hipMemsetAsync(acc, 0, (size_t)N_NODES * 512 * sizeof(float), stream);

    k_node_in <<<N_NODES / 4, 256, 0, stream>>>(ni, attr, deg, Wli0, Wli1,
                                                Wlm0, Wlm1, f, out);
    k_edge    <<<N_EDGES / 4, 256, 0, stream>>>(eattr, elen, Wm1, Wm2,
                                                esrc, edst, f, acc);
    k_node_out<<<N_NODES / 4, 256, 0, stream>>>(acc, attr, deg, Wlo0, Wlo1, out);
}

// Round 2
// 577.724 us; speedup vs baseline: 2.1989x; 2.1989x over previous
//
#include <hip/hip_runtime.h>
#include <hip/hip_bf16.h>
#include <math.h>

#define N_NODES 20000
#define N_EDGES 320000

#define INV1   0.31622776601683794f   // 1/sqrt(10)
#define SC2    0.1f                   // 1/sqrt(100)
#define IS3    0.5773502691896258f    // 1/sqrt(3)
#define C_S    0.3826834323650898f    // sin(pi/8)
#define C_X    0.9238795325112867f    // cos(pi/8)
#define INV64  0.125f                 // 1/sqrt(64)
#define INVLO  0.08838834764831845f   // 1/sqrt(128)

__device__ __forceinline__ float silu_f(float x) {
    return x / (1.0f + expf(-x));
}

// ---------------- node pre-pass: f = [f0|f1] (deg-scaled), out = c_s * m ----
__global__ __launch_bounds__(256) void k_node_in(
    const float* __restrict__ ni, const float* __restrict__ attr,
    const float* __restrict__ deg,
    const float* __restrict__ Wli0, const float* __restrict__ Wli1,
    const float* __restrict__ Wlm0, const float* __restrict__ Wlm1,
    float* __restrict__ f, float* __restrict__ out)
{
    __shared__ float raw[4][256];
    const int wave = threadIdx.x >> 6;
    const int lane = threadIdx.x & 63;
    const int n = blockIdx.x * 4 + wave;

    const float* row = ni + (size_t)n * 256;
    raw[wave][lane      ] = row[lane      ];
    raw[wave][lane + 64 ] = row[lane + 64 ];
    raw[wave][lane + 128] = row[lane + 128];
    raw[wave][lane + 192] = row[lane + 192];
    __syncthreads();

    float f0 = 0.f, m0 = 0.f;
    float f1x = 0.f, f1y = 0.f, f1z = 0.f;
    float m1x = 0.f, m1y = 0.f, m1z = 0.f;
    #pragma unroll 4
    for (int t = 0; t < 64; ++t) {
        float xs  = raw[wave][t];
        float xv0 = raw[wave][64 + t*3    ];
        float xv1 = raw[wave][64 + t*3 + 1];
        float xv2 = raw[wave][64 + t*3 + 2];
        float a0 = Wli0[t*64 + lane];
        float a1 = Wli1[t*64 + lane];
        float b0 = Wlm0[t*64 + lane];
        float b1 = Wlm1[t*64 + lane];
        f0  += xs  * a0;   m0  += xs  * b0;
        f1x += xv0 * a1;   f1y += xv1 * a1;   f1z += xv2 * a1;
        m1x += xv0 * b1;   m1y += xv1 * b1;   m1z += xv2 * b1;
    }

    const float a   = attr[n] * INV64;
    const float dis = 1.0f / sqrtf(deg[n]);
    const float fa  = a * dis;

    float* fr = f + (size_t)n * 256;
    fr[lane      ] = f0  * fa;
    fr[64  + lane] = f1x * fa;
    fr[128 + lane] = f1y * fa;
    fr[192 + lane] = f1z * fa;

    float* orow = out + (size_t)n * 256;
    orow[lane] = C_S * m0 * a;
    orow[64 + lane*3    ] = C_S * m1x * a;
    orow[64 + lane*3 + 1] = C_S * m1y * a;
    orow[64 + lane*3 + 2] = C_S * m1z * a;
}

// ---------------- edge MLP as blocked GEMM: ew[e][256] (bf16) ---------------
// 64 edges per block. W2 read ONCE per block (was: once per edge).
__global__ __launch_bounds__(256) void k_mlp(
    const float* __restrict__ elen, const float* __restrict__ W1,
    const float* __restrict__ W2, __hip_bfloat16* __restrict__ ew)
{
    __shared__ float Xs[64 * 11];      // padded stride 11 (bank-conflict-free)
    __shared__ float W1s[10 * 100];
    __shared__ float Hs[100][64];      // k-major: GEMM reads are broadcasts
    const int t  = threadIdx.x;
    const int e0 = blockIdx.x * 64;

    for (int i = t; i < 640; i += 256) {
        float v = elen[(size_t)e0 * 10 + i];
        Xs[(i / 10) * 11 + (i % 10)] = v;
    }
    for (int i = t; i < 1000; i += 256) W1s[i] = W1[i];
    __syncthreads();

    // H[j][e] = silu( (X[e,:] . W1[:,j]) * INV1 ),  thread covers 25 j's
    {
        const int e = t & 63;
        #pragma unroll
        for (int i = 0; i < 25; ++i) {
            const int j = (t >> 6) + 4 * i;
            float a = 0.f;
            #pragma unroll
            for (int b = 0; b < 10; ++b) a += Xs[e*11 + b] * W1s[b*100 + j];
            a *= INV1;
            Hs[j][e] = silu_f(a);
        }
    }
    __syncthreads();

    // EW tile: thread -> cols {tc,tc+64,tc+128,tc+192}, edges eg+4i (i<16)
    const int tc = t & 63, eg = t >> 6;
    float acc[16][4];
    #pragma unroll
    for (int i = 0; i < 16; ++i) { acc[i][0]=0.f; acc[i][1]=0.f; acc[i][2]=0.f; acc[i][3]=0.f; }

    for (int k = 0; k < 100; ++k) {
        const float w0 = W2[k*256 + tc      ];
        const float w1 = W2[k*256 + 64  + tc];
        const float w2 = W2[k*256 + 128 + tc];
        const float w3 = W2[k*256 + 192 + tc];
        #pragma unroll
        for (int i = 0; i < 16; ++i) {
            const float h = Hs[k][eg + 4*i];   // wave-uniform -> broadcast
            acc[i][0] += h * w0;
            acc[i][1] += h * w1;
            acc[i][2] += h * w2;
            acc[i][3] += h * w3;
        }
    }

    #pragma unroll
    for (int i = 0; i < 16; ++i) {
        const int e = e0 + eg + 4*i;
        __hip_bfloat16* er = ew + (size_t)e * 256;
        er[tc      ] = __float2bfloat16(acc[i][0] * SC2);
        er[64  + tc] = __float2bfloat16(acc[i][1] * SC2);
        er[128 + tc] = __float2bfloat16(acc[i][2] * SC2);
        er[192 + tc] = __float2bfloat16(acc[i][3] * SC2);
    }
}

// ---------------- counting sort of edges by dst -----------------------------
__global__ __launch_bounds__(256) void k_hist(const int* __restrict__ edst,
                                              int* __restrict__ hist) {
    const int e = blockIdx.x * 256 + threadIdx.x;
    if (e < N_EDGES) atomicAdd(&hist[edst[e]], 1);
}

__global__ __launch_bounds__(1024) void k_scan(const int* __restrict__ hist,
                                               int* __restrict__ starts,
                                               int* __restrict__ cursor) {
    __shared__ int part[1024];
    const int t = threadIdx.x;
    const int C = 20;                     // 1024*20 >= 20000
    const int base = t * C;
    int s = 0;
    for (int i = 0; i < C; ++i) {
        const int idx = base + i;
        if (idx < N_NODES) s += hist[idx];
    }
    part[t] = s;
    __syncthreads();
    for (int off = 1; off < 1024; off <<= 1) {
        int v = (t >= off) ? part[t - off] : 0;
        __syncthreads();
        part[t] += v;
        __syncthreads();
    }
    int run = part[t] - s;                // exclusive prefix
    for (int i = 0; i < C; ++i) {
        const int idx = base + i;
        if (idx < N_NODES) {
            starts[idx] = run;
            cursor[idx] = run;
            run += hist[idx];
        }
    }
    if (t == 1023) starts[N_NODES] = N_EDGES;
}

__global__ __launch_bounds__(256) void k_scatter(const int* __restrict__ edst,
                                                 int* __restrict__ cursor,
                                                 int* __restrict__ elist) {
    const int e = blockIdx.x * 256 + threadIdx.x;
    if (e < N_EDGES) {
        const int p = atomicAdd(&cursor[edst[e]], 1);
        elist[p] = e;
    }
}

// ---------------- per-dst gather + fused W_lo GEMM + epilogue ---------------
__global__ __launch_bounds__(256) void k_gather(
    const int* __restrict__ starts, const int* __restrict__ elist,
    const int* __restrict__ esrc, const float* __restrict__ eattr,
    const __hip_bfloat16* __restrict__ ew, const float* __restrict__ f,
    const float* __restrict__ attr, const float* __restrict__ deg,
    const float* __restrict__ Wlo0, const float* __restrict__ Wlo1,
    float* __restrict__ out)
{
    __shared__ float sm[4][512];
    const int wave = threadIdx.x >> 6;
    const int lane = threadIdx.x & 63;
    const int n = blockIdx.x * 4 + wave;

    const int beg = starts[n], end = starts[n + 1];
    float sA=0.f, sB=0.f;
    float vA0=0.f, vA1=0.f, vA2=0.f;
    float vB0=0.f, vB1=0.f, vB2=0.f;

    for (int j = beg; j < end; ++j) {
        const int e   = elist[j];
        const int src = esrc[e];
        const float y0  = eattr[e*4 + 0];
        const float y10 = eattr[e*4 + 1];
        const float y11 = eattr[e*4 + 2];
        const float y12 = eattr[e*4 + 3];

        const __hip_bfloat16* wr = ew + (size_t)e * 256;
        const float wa = __bfloat162float(wr[lane      ]);
        const float wb = __bfloat162float(wr[64  + lane]);
        const float wc = __bfloat162float(wr[128 + lane]);
        const float wd = __bfloat162float(wr[192 + lane]);

        const float* fr = f + (size_t)src * 256;
        const float g0  = fr[lane      ];
        const float g10 = fr[64  + lane];
        const float g11 = fr[128 + lane];
        const float g12 = fr[192 + lane];

        const float dotv = g10*y10 + g11*y11 + g12*y12;
        sA += wa * g0 * y0;
        sB += wb * dotv;
        const float t0 = wc * g0;
        vA0 += t0 * y10;  vA1 += t0 * y11;  vA2 += t0 * y12;
        const float t1 = wd * y0;
        vB0 += t1 * g10;  vB1 += t1 * g11;  vB2 += t1 * g12;
    }

    const float dis = 1.0f / sqrtf(deg[n]);
    sm[wave][lane        ] = sA * dis;
    sm[wave][64  + lane  ] = sB * IS3 * dis;
    sm[wave][128 + lane      ] = vA0 * dis;
    sm[wave][128 + 64 + lane ] = vB0 * dis;
    sm[wave][256 + lane      ] = vA1 * dis;
    sm[wave][256 + 64 + lane ] = vB1 * dis;
    sm[wave][384 + lane      ] = vA2 * dis;
    sm[wave][384 + 64 + lane ] = vB2 * dis;
    __syncthreads();

    float o0=0.f, o1x=0.f, o1y=0.f, o1z=0.f;
    #pragma unroll 4
    for (int c = 0; c < 128; ++c) {
        const float w0 = Wlo0[c*64 + lane];
        const float w1 = Wlo1[c*64 + lane];
        o0  += sm[wave][c]         * w0;
        o1x += sm[wave][128 + c]   * w1;
        o1y += sm[wave][256 + c]   * w1;
        o1z += sm[wave][384 + c]   * w1;
    }

    const float a = attr[n] * INVLO;
    float* orow = out + (size_t)n * 256;
    orow[lane] += C_X * o0 * a;
    orow[64 + lane*3    ] += C_X * o1x * a;
    orow[64 + lane*3 + 1] += C_X * o1y * a;
    orow[64 + lane*3 + 2] += C_X * o1z * a;
}

// ======================= fallback (round-1) path ============================
__global__ __launch_bounds__(256) void k_edge_legacy(
    const float* __restrict__ eattr, const float* __restrict__ elen,
    const float* __restrict__ W1, const float* __restrict__ W2,
    const int* __restrict__ esrc, const int* __restrict__ edst,
    const float* __restrict__ f, float* __restrict__ acc)
{
    __shared__ float hsh[4][104];
    const int wave = threadIdx.x >> 6;
    const int lane = threadIdx.x & 63;
    const int e = blockIdx.x * 4 + wave;

    const float* el = elen + (size_t)e * 10;
    float elr[10];
    #pragma unroll
    for (int b = 0; b < 10; ++b) elr[b] = el[b];

    float a1 = 0.f;
    #pragma unroll
    for (int b = 0; b < 10; ++b) a1 += elr[b] * W1[b*100 + lane];
    hsh[wave][lane] = silu_f(a1 * INV1);
    if (lane < 36) {
        float a2 = 0.f;
        #pragma unroll
        for (int b = 0; b < 10; ++b) a2 += elr[b] * W1[b*100 + 64 + lane];
        hsh[wave][64 + lane] = silu_f(a2 * INV1);
    }
    __syncthreads();

    float wa = 0.f, wb = 0.f, wc = 0.f, wd = 0.f;
    #pragma unroll 4
    for (int j = 0; j < 100; ++j) {
        float hj = hsh[wave][j];
        const float* wr = W2 + j*256;
        wa += hj * wr[lane      ];
        wb += hj * wr[64  + lane];
        wc += hj * wr[128 + lane];
        wd += hj * wr[192 + lane];
    }
    wa *= SC2; wb *= SC2; wc *= SC2; wd *= SC2;

    const int src = esrc[e];
    const int dst = edst[e];
    const float y0  = eattr[e*4 + 0];
    const float y10 = eattr[e*4 + 1];
    const float y11 = eattr[e*4 + 2];
    const float y12 = eattr[e*4 + 3];

    const float* fr = f + (size_t)src * 256;
    const float g0  = fr[lane      ];
    const float g10 = fr[64  + lane];
    const float g11 = fr[128 + lane];
    const float g12 = fr[192 + lane];

    const float dotv = g10*y10 + g11*y11 + g12*y12;

    float* ar = acc + (size_t)dst * 512;
    atomicAdd(ar + lane,                  wa * g0 * y0);
    atomicAdd(ar + 64 + lane,             wb * dotv * IS3);
    atomicAdd(ar + 128 +   0 + lane,      wc * g0 * y10);
    atomicAdd(ar + 128 + 128 + lane,      wc * g0 * y11);
    atomicAdd(ar + 128 + 256 + lane,      wc * g0 * y12);
    atomicAdd(ar + 128 +   0 + 64 + lane, wd * g10 * y0);
    atomicAdd(ar + 128 + 128 + 64 + lane, wd * g11 * y0);
    atomicAdd(ar + 128 + 256 + 64 + lane, wd * g12 * y0);
}

__global__ __launch_bounds__(256) void k_node_out_legacy(
    const float* __restrict__ acc, const float* __restrict__ attr,
    const float* __restrict__ deg, const float* __restrict__ Wlo0,
    const float* __restrict__ Wlo1, float* __restrict__ out)
{
    __shared__ float sm[4][512];
    const int wave = threadIdx.x >> 6;
    const int lane = threadIdx.x & 63;
    const int n = blockIdx.x * 4 + wave;

    const float dis = 1.0f / sqrtf(deg[n]);
    const float* ar = acc + (size_t)n * 512;
    #pragma unroll
    for (int i = lane; i < 512; i += 64) sm[wave][i] = ar[i] * dis;
    __syncthreads();

    float o0 = 0.f, o1x = 0.f, o1y = 0.f, o1z = 0.f;
    #pragma unroll 4
    for (int c = 0; c < 128; ++c) {
        float w0 = Wlo0[c*64 + lane];
        float w1 = Wlo1[c*64 + lane];
        o0  += sm[wave][c]        * w0;
        o1x += sm[wave][128 + c]  * w1;
        o1y += sm[wave][256 + c]  * w1;
        o1z += sm[wave][384 + c]  * w1;
    }

    const float a = attr[n] * INVLO;
    float* orow = out + (size_t)n * 256;
    orow[lane] += C_X * o0 * a;
    orow[64 + lane*3    ] += C_X * o1x * a;
    orow[64 + lane*3 + 1] += C_X * o1y * a;
    orow[64 + lane*3 + 2] += C_X * o1z * a;
}

// ============================================================================
extern "C" void kernel_launch(void* const* d_in, const int* in_sizes, int n_in,
                              void* d_out, int out_size, void* d_ws, size_t ws_size,
                              hipStream_t stream) {
    const float* ni    = (const float*)d_in[0];
    const float* attr  = (const float*)d_in[1];
    const float* deg   = (const float*)d_in[2];
    const float* eattr = (const float*)d_in[3];
    const float* elen  = (const float*)d_in[4];
    const float* Wli0  = (const float*)d_in[5];
    const float* Wli1  = (const float*)d_in[6];
    const float* Wlm0  = (const float*)d_in[7];
    const float* Wlm1  = (const float*)d_in[8];
    const float* Wm1   = (const float*)d_in[9];
    const float* Wm2   = (const float*)d_in[10];
    const float* Wlo0  = (const float*)d_in[11];
    const float* Wlo1  = (const float*)d_in[12];
    const int*   esrc  = (const int*)d_in[13];
    const int*   edst  = (const int*)d_in[14];

    float* out = (float*)d_out;

    // ws layout (fast path)
    char* wsb = (char*)d_ws;
    float* f = (float*)wsb;                                    // 20,480,000 B
    size_t off = (size_t)N_NODES * 256 * sizeof(float);
    __hip_bfloat16* ew = (__hip_bfloat16*)(wsb + off);         // 163,840,000 B
    off += (size_t)N_EDGES * 256 * sizeof(__hip_bfloat16);
    int* elist = (int*)(wsb + off);  off += (size_t)N_EDGES * sizeof(int);
    int* starts = (int*)(wsb + off); off += (size_t)(N_NODES + 4) * sizeof(int);
    int* hist = (int*)(wsb + off);   off += (size_t)N_NODES * sizeof(int);
    int* cursor = (int*)(wsb + off); off += (size_t)N_NODES * sizeof(int);
    const size_t need_fast = off;

    if (ws_size >= need_fast) {
        hipMemsetAsync(hist, 0, (size_t)N_NODES * sizeof(int), stream);
        k_node_in<<<N_NODES / 4, 256, 0, stream>>>(ni, attr, deg, Wli0, Wli1,
                                                   Wlm0, Wlm1, f, out);
        k_hist   <<<N_EDGES / 256, 256, 0, stream>>>(edst, hist);
        k_scan   <<<1, 1024, 0, stream>>>(hist, starts, cursor);
        k_scatter<<<N_EDGES / 256, 256, 0, stream>>>(edst, cursor, elist);
        k_mlp    <<<N_EDGES / 64, 256, 0, stream>>>(elen, Wm1, Wm2, ew);
        k_gather <<<N_NODES / 4, 256, 0, stream>>>(starts, elist, esrc, eattr,
                                                   ew, f, attr, deg, Wlo0, Wlo1, out);
    } else {
        // fallback: round-1 atomic path (61.4 MB scratch)
        float* acc = f + (size_t)N_NODES * 256;
        hipMemsetAsync(acc, 0, (size_t)N_NODES * 512 * sizeof(float), stream);
        k_node_in<<<N_NODES / 4, 256, 0, stream>>>(ni, attr, deg, Wli0, Wli1,
                                                   Wlm0, Wlm1, f, out);
        k_edge_legacy<<<N_EDGES / 4, 256, 0, stream>>>(eattr, elen, Wm1, Wm2,
                                                       esrc, edst, f, acc);
        k_node_out_legacy<<<N_NODES / 4, 256, 0, stream>>>(acc, attr, deg,
                                                           Wlo0, Wlo1, out);
    }
}

// Round 3
// 463.611 us; speedup vs baseline: 2.7401x; 1.2461x over previous
//
#include <hip/hip_runtime.h>
#include <hip/hip_bf16.h>
#include <math.h>

#define N_NODES 20000
#define N_EDGES 320000

#define INV1   0.31622776601683794f   // 1/sqrt(10)
#define SC2    0.1f                   // 1/sqrt(100)
#define IS3    0.5773502691896258f    // 1/sqrt(3)
#define C_S    0.3826834323650898f    // sin(pi/8)
#define C_X    0.9238795325112867f    // cos(pi/8)
#define INV64  0.125f                 // 1/sqrt(64)
#define INVLO  0.08838834764831845f   // 1/sqrt(128)

typedef short     short8 __attribute__((ext_vector_type(8)));
typedef float     f32x4  __attribute__((ext_vector_type(4)));

__device__ __forceinline__ float silu_f(float x) {
    return x / (1.0f + expf(-x));
}
__device__ __forceinline__ unsigned short f2bf(float x) {
    __hip_bfloat16 h = __float2bfloat16(x);
    return *reinterpret_cast<unsigned short*>(&h);
}
__device__ __forceinline__ float bf2f(unsigned short u) {
    __hip_bfloat16 h;
    *reinterpret_cast<unsigned short*>(&h) = u;
    return __bfloat162float(h);
}

// ---------------- node pre-pass: f packed [n][64] float4, out = c_s * m ----
__global__ __launch_bounds__(256) void k_node_in(
    const float* __restrict__ ni, const float* __restrict__ attr,
    const float* __restrict__ deg,
    const float* __restrict__ Wli0, const float* __restrict__ Wli1,
    const float* __restrict__ Wlm0, const float* __restrict__ Wlm1,
    float4* __restrict__ fv, float* __restrict__ out)
{
    __shared__ float raw[4][256];
    const int wave = threadIdx.x >> 6;
    const int lane = threadIdx.x & 63;
    const int n = blockIdx.x * 4 + wave;

    const float* row = ni + (size_t)n * 256;
    raw[wave][lane      ] = row[lane      ];
    raw[wave][lane + 64 ] = row[lane + 64 ];
    raw[wave][lane + 128] = row[lane + 128];
    raw[wave][lane + 192] = row[lane + 192];
    __syncthreads();

    float f0 = 0.f, m0 = 0.f;
    float f1x = 0.f, f1y = 0.f, f1z = 0.f;
    float m1x = 0.f, m1y = 0.f, m1z = 0.f;
    #pragma unroll 4
    for (int t = 0; t < 64; ++t) {
        float xs  = raw[wave][t];
        float xv0 = raw[wave][64 + t*3    ];
        float xv1 = raw[wave][64 + t*3 + 1];
        float xv2 = raw[wave][64 + t*3 + 2];
        float a0 = Wli0[t*64 + lane];
        float a1 = Wli1[t*64 + lane];
        float b0 = Wlm0[t*64 + lane];
        float b1 = Wlm1[t*64 + lane];
        f0  += xs  * a0;   m0  += xs  * b0;
        f1x += xv0 * a1;   f1y += xv1 * a1;   f1z += xv2 * a1;
        m1x += xv0 * b1;   m1y += xv1 * b1;   m1z += xv2 * b1;
    }

    const float a   = attr[n] * INV64;
    const float dis = 1.0f / sqrtf(deg[n]);
    const float fa  = a * dis;

    fv[(size_t)n * 64 + lane] = make_float4(f0*fa, f1x*fa, f1y*fa, f1z*fa);

    float* orow = out + (size_t)n * 256;
    orow[lane] = C_S * m0 * a;
    orow[64 + lane*3    ] = C_S * m1x * a;
    orow[64 + lane*3 + 1] = C_S * m1y * a;
    orow[64 + lane*3 + 2] = C_S * m1z * a;
}

// ---------------- counting sort by dst + sorted edge data -------------------
__global__ __launch_bounds__(256) void k_hist(const int* __restrict__ edst,
                                              int* __restrict__ hist) {
    const int e = blockIdx.x * 256 + threadIdx.x;
    if (e < N_EDGES) atomicAdd(&hist[edst[e]], 1);
}

__global__ __launch_bounds__(1024) void k_scan(const int* __restrict__ hist,
                                               int* __restrict__ starts,
                                               int* __restrict__ cursor) {
    __shared__ int part[1024];
    const int t = threadIdx.x;
    const int C = 20;
    const int base = t * C;
    int s = 0;
    for (int i = 0; i < C; ++i) {
        const int idx = base + i;
        if (idx < N_NODES) s += hist[idx];
    }
    part[t] = s;
    __syncthreads();
    for (int off = 1; off < 1024; off <<= 1) {
        int v = (t >= off) ? part[t - off] : 0;
        __syncthreads();
        part[t] += v;
        __syncthreads();
    }
    int run = part[t] - s;
    for (int i = 0; i < C; ++i) {
        const int idx = base + i;
        if (idx < N_NODES) {
            starts[idx] = run;
            cursor[idx] = run;
            run += hist[idx];
        }
    }
    if (t == 1023) starts[N_NODES] = N_EDGES;
}

__global__ __launch_bounds__(256) void k_scatter(
    const int* __restrict__ esrc, const int* __restrict__ edst,
    const float4* __restrict__ eattr4, int* __restrict__ cursor,
    int* __restrict__ perm, int* __restrict__ esrc_s,
    float4* __restrict__ eattrs)
{
    const int e = blockIdx.x * 256 + threadIdx.x;
    if (e < N_EDGES) {
        const int p = atomicAdd(&cursor[edst[e]], 1);
        perm[e] = p;
        esrc_s[p] = esrc[e];
        eattrs[p] = eattr4[e];
    }
}

// ---------------- W2 -> bf16 transposed [256 n][128 k] ----------------------
__global__ __launch_bounds__(256) void k_w2t(const float* __restrict__ W2,
                                             unsigned short* __restrict__ w2t) {
    const int i = blockIdx.x * 256 + threadIdx.x;   // 32768
    const int n = i >> 7, k = i & 127;
    w2t[i] = (k < 100) ? f2bf(W2[k*256 + n]) : (unsigned short)0;
}

// ---------------- edge MLP, MFMA: ew[p][256] bf16 (sorted rows) -------------
// 128 edges/block, 32/wave. H = silu(X*W1/sqrt10) via one 16x16x32 MFMA step;
// big GEMM H[32x128] * W2T -> [32x256] via 128 MFMA/wave.
__global__ __launch_bounds__(256) void k_mlp(
    const float* __restrict__ elen, const float* __restrict__ W1,
    const unsigned short* __restrict__ w2t, const int* __restrict__ perm,
    __hip_bfloat16* __restrict__ ew)
{
    __shared__ unsigned short Xs[128 * 40];    // [e][k], k 0..31 (10 real), pad
    __shared__ unsigned short W1T[112 * 40];   // [n][k], k 0..31 (10 real)
    __shared__ unsigned short Hs[128 * 136];   // [e][k], k 0..127 (100 real)
    const int t  = threadIdx.x;
    const int e0 = blockIdx.x * 128;

    // stage X (bf16) + zero pad cols 10..31
    for (int i = t; i < 1280; i += 256) {
        const int e = i / 10, b = i % 10;
        Xs[e*40 + b] = f2bf(elen[(size_t)(e0 + e) * 10 + b]);
    }
    for (int i = t; i < 128*22; i += 256) {
        const int e = i / 22, c = 10 + i % 22;
        Xs[e*40 + c] = 0;
    }
    // stage W1 transposed (bf16), zeros for k>=10 or n>=100
    for (int i = t; i < 112*32; i += 256) {
        const int n = i >> 5, k = i & 31;
        W1T[n*40 + k] = (k < 10 && n < 100) ? f2bf(W1[k*100 + n]) : (unsigned short)0;
    }
    // zero Hs cols 112..135 (cols 100..111 become silu(0)=0 naturally)
    for (int i = t; i < 128*24; i += 256) {
        const int e = i / 24, c = 112 + i % 24;
        Hs[e*136 + c] = 0;
    }
    __syncthreads();

    const int w   = t >> 6;
    const int m15 = t & 15;
    const int q   = (t & 63) >> 4;
    const int eb  = w * 32;                    // wave's edge base (local)

    // ---- H GEMM: one K=32 step, 7 n-tiles ----
    short8 xa0 = *(const short8*)&Xs[(eb      + m15)*40 + q*8];
    short8 xa1 = *(const short8*)&Xs[(eb + 16 + m15)*40 + q*8];
    for (int nt = 0; nt < 7; ++nt) {
        short8 bw = *(const short8*)&W1T[(nt*16 + m15)*40 + q*8];
        f32x4 z = {0.f, 0.f, 0.f, 0.f};
        f32x4 h0 = __builtin_amdgcn_mfma_f32_16x16x32_bf16(xa0, bw, z, 0, 0, 0);
        f32x4 h1 = __builtin_amdgcn_mfma_f32_16x16x32_bf16(xa1, bw, z, 0, 0, 0);
        #pragma unroll
        for (int r = 0; r < 4; ++r) {
            // D: col = m15 (n), row = q*4+r (edge)
            Hs[(eb      + q*4 + r)*136 + nt*16 + m15] = f2bf(silu_f(h0[r] * INV1));
            Hs[(eb + 16 + q*4 + r)*136 + nt*16 + m15] = f2bf(silu_f(h1[r] * INV1));
        }
    }
    // same wave wrote its own rows -> no barrier needed (compiler waits lgkmcnt)

    // ---- big GEMM: A-frags (hoisted), B from global W2T (L2) ----
    short8 A0[4], A1[4];
    #pragma unroll
    for (int s = 0; s < 4; ++s) {
        A0[s] = *(const short8*)&Hs[(eb      + m15)*136 + s*32 + q*8];
        A1[s] = *(const short8*)&Hs[(eb + 16 + m15)*136 + s*32 + q*8];
    }
    int prm[8];
    #pragma unroll
    for (int mt = 0; mt < 2; ++mt)
        #pragma unroll
        for (int r = 0; r < 4; ++r)
            prm[mt*4 + r] = perm[e0 + eb + mt*16 + q*4 + r];

    for (int nt = 0; nt < 16; ++nt) {
        f32x4 c0 = {0.f,0.f,0.f,0.f}, c1 = {0.f,0.f,0.f,0.f};
        const unsigned short* bp = w2t + ((size_t)(nt*16 + m15) << 7);
        #pragma unroll
        for (int s = 0; s < 4; ++s) {
            short8 B = *(const short8*)(bp + s*32 + q*8);
            c0 = __builtin_amdgcn_mfma_f32_16x16x32_bf16(A0[s], B, c0, 0, 0, 0);
            c1 = __builtin_amdgcn_mfma_f32_16x16x32_bf16(A1[s], B, c1, 0, 0, 0);
        }
        const int col = nt*16 + m15;
        #pragma unroll
        for (int r = 0; r < 4; ++r) {
            ew[(size_t)prm[r]    *256 + col] = __float2bfloat16(c0[r] * SC2);
            ew[(size_t)prm[4 + r]*256 + col] = __float2bfloat16(c1[r] * SC2);
        }
    }
}

// ---------------- per-dst gather + fused W_lo GEMM + epilogue ---------------
__global__ __launch_bounds__(256) void k_gather(
    const int* __restrict__ starts, const int* __restrict__ esrc_s,
    const float4* __restrict__ eattrs, const __hip_bfloat16* __restrict__ ew,
    const float4* __restrict__ fv,
    const float* __restrict__ attr, const float* __restrict__ deg,
    const float* __restrict__ Wlo0, const float* __restrict__ Wlo1,
    float* __restrict__ out)
{
    __shared__ float sm[4][512];
    const int wave = threadIdx.x >> 6;
    const int lane = threadIdx.x & 63;
    const int n = blockIdx.x * 4 + wave;

    const int beg = starts[n], end = starts[n + 1];
    float sA=0.f, sB=0.f;
    float vA0=0.f, vA1=0.f, vA2=0.f;
    float vB0=0.f, vB1=0.f, vB2=0.f;

    for (int base = beg; base < end; base += 64) {
        const int cnt = min(64, end - base);
        int    srcv = 0;
        float4 eav  = make_float4(0.f, 0.f, 0.f, 0.f);
        if (lane < cnt) {
            srcv = esrc_s[base + lane];
            eav  = eattrs[base + lane];
        }
        for (int j = 0; j < cnt; ++j) {
            const int   src = __shfl(srcv, j);
            const float y0  = __shfl(eav.x, j);
            const float y10 = __shfl(eav.y, j);
            const float y11 = __shfl(eav.z, j);
            const float y12 = __shfl(eav.w, j);

            const __hip_bfloat16* wr = ew + (size_t)(base + j) * 256;
            const float wa = __bfloat162float(wr[lane      ]);
            const float wb = __bfloat162float(wr[64  + lane]);
            const float wc = __bfloat162float(wr[128 + lane]);
            const float wd = __bfloat162float(wr[192 + lane]);

            const float4 g = fv[(size_t)src * 64 + lane];

            const float dotv = g.y*y10 + g.z*y11 + g.w*y12;
            sA += wa * g.x * y0;
            sB += wb * dotv;
            const float t0 = wc * g.x;
            vA0 += t0 * y10;  vA1 += t0 * y11;  vA2 += t0 * y12;
            const float t1 = wd * y0;
            vB0 += t1 * g.y;  vB1 += t1 * g.z;  vB2 += t1 * g.w;
        }
    }

    const float dis = 1.0f / sqrtf(deg[n]);
    sm[wave][lane            ] = sA * dis;
    sm[wave][64  + lane      ] = sB * IS3 * dis;
    sm[wave][128 + lane      ] = vA0 * dis;
    sm[wave][128 + 64 + lane ] = vB0 * dis;
    sm[wave][256 + lane      ] = vA1 * dis;
    sm[wave][256 + 64 + lane ] = vB1 * dis;
    sm[wave][384 + lane      ] = vA2 * dis;
    sm[wave][384 + 64 + lane ] = vB2 * dis;
    __syncthreads();

    float o0=0.f, o1x=0.f, o1y=0.f, o1z=0.f;
    #pragma unroll 4
    for (int c = 0; c < 128; ++c) {
        const float w0 = Wlo0[c*64 + lane];
        const float w1 = Wlo1[c*64 + lane];
        o0  += sm[wave][c]         * w0;
        o1x += sm[wave][128 + c]   * w1;
        o1y += sm[wave][256 + c]   * w1;
        o1z += sm[wave][384 + c]   * w1;
    }

    const float a = attr[n] * INVLO;
    float* orow = out + (size_t)n * 256;
    orow[lane] += C_X * o0 * a;
    orow[64 + lane*3    ] += C_X * o1x * a;
    orow[64 + lane*3 + 1] += C_X * o1y * a;
    orow[64 + lane*3 + 2] += C_X * o1z * a;
}

// ======================= fallback (round-1) path ============================
__global__ __launch_bounds__(256) void k_node_in_legacy(
    const float* __restrict__ ni, const float* __restrict__ attr,
    const float* __restrict__ deg,
    const float* __restrict__ Wli0, const float* __restrict__ Wli1,
    const float* __restrict__ Wlm0, const float* __restrict__ Wlm1,
    float* __restrict__ f, float* __restrict__ out)
{
    __shared__ float raw[4][256];
    const int wave = threadIdx.x >> 6;
    const int lane = threadIdx.x & 63;
    const int n = blockIdx.x * 4 + wave;

    const float* row = ni + (size_t)n * 256;
    raw[wave][lane      ] = row[lane      ];
    raw[wave][lane + 64 ] = row[lane + 64 ];
    raw[wave][lane + 128] = row[lane + 128];
    raw[wave][lane + 192] = row[lane + 192];
    __syncthreads();

    float f0 = 0.f, m0 = 0.f;
    float f1x = 0.f, f1y = 0.f, f1z = 0.f;
    float m1x = 0.f, m1y = 0.f, m1z = 0.f;
    for (int t = 0; t < 64; ++t) {
        float xs  = raw[wave][t];
        float xv0 = raw[wave][64 + t*3    ];
        float xv1 = raw[wave][64 + t*3 + 1];
        float xv2 = raw[wave][64 + t*3 + 2];
        float a0 = Wli0[t*64 + lane];
        float a1 = Wli1[t*64 + lane];
        float b0 = Wlm0[t*64 + lane];
        float b1 = Wlm1[t*64 + lane];
        f0  += xs  * a0;   m0  += xs  * b0;
        f1x += xv0 * a1;   f1y += xv1 * a1;   f1z += xv2 * a1;
        m1x += xv0 * b1;   m1y += xv1 * b1;   m1z += xv2 * b1;
    }

    const float a   = attr[n] * INV64;
    const float dis = 1.0f / sqrtf(deg[n]);
    const float fa  = a * dis;

    float* fr = f + (size_t)n * 256;
    fr[lane      ] = f0  * fa;
    fr[64  + lane] = f1x * fa;
    fr[128 + lane] = f1y * fa;
    fr[192 + lane] = f1z * fa;

    float* orow = out + (size_t)n * 256;
    orow[lane] = C_S * m0 * a;
    orow[64 + lane*3    ] = C_S * m1x * a;
    orow[64 + lane*3 + 1] = C_S * m1y * a;
    orow[64 + lane*3 + 2] = C_S * m1z * a;
}

__global__ __launch_bounds__(256) void k_edge_legacy(
    const float* __restrict__ eattr, const float* __restrict__ elen,
    const float* __restrict__ W1, const float* __restrict__ W2,
    const int* __restrict__ esrc, const int* __restrict__ edst,
    const float* __restrict__ f, float* __restrict__ acc)
{
    __shared__ float hsh[4][104];
    const int wave = threadIdx.x >> 6;
    const int lane = threadIdx.x & 63;
    const int e = blockIdx.x * 4 + wave;

    const float* el = elen + (size_t)e * 10;
    float elr[10];
    #pragma unroll
    for (int b = 0; b < 10; ++b) elr[b] = el[b];

    float a1 = 0.f;
    #pragma unroll
    for (int b = 0; b < 10; ++b) a1 += elr[b] * W1[b*100 + lane];
    hsh[wave][lane] = silu_f(a1 * INV1);
    if (lane < 36) {
        float a2 = 0.f;
        #pragma unroll
        for (int b = 0; b < 10; ++b) a2 += elr[b] * W1[b*100 + 64 + lane];
        hsh[wave][64 + lane] = silu_f(a2 * INV1);
    }
    __syncthreads();

    float wa = 0.f, wb = 0.f, wc = 0.f, wd = 0.f;
    for (int j = 0; j < 100; ++j) {
        float hj = hsh[wave][j];
        const float* wr = W2 + j*256;
        wa += hj * wr[lane      ];
        wb += hj * wr[64  + lane];
        wc += hj * wr[128 + lane];
        wd += hj * wr[192 + lane];
    }
    wa *= SC2; wb *= SC2; wc *= SC2; wd *= SC2;

    const int src = esrc[e];
    const int dst = edst[e];
    const float y0  = eattr[e*4 + 0];
    const float y10 = eattr[e*4 + 1];
    const float y11 = eattr[e*4 + 2];
    const float y12 = eattr[e*4 + 3];

    const float* fr = f + (size_t)src * 256;
    const float g0  = fr[lane      ];
    const float g10 = fr[64  + lane];
    const float g11 = fr[128 + lane];
    const float g12 = fr[192 + lane];

    const float dotv = g10*y10 + g11*y11 + g12*y12;

    float* ar = acc + (size_t)dst * 512;
    atomicAdd(ar + lane,                  wa * g0 * y0);
    atomicAdd(ar + 64 + lane,             wb * dotv * IS3);
    atomicAdd(ar + 128 +   0 + lane,      wc * g0 * y10);
    atomicAdd(ar + 128 + 128 + lane,      wc * g0 * y11);
    atomicAdd(ar + 128 + 256 + lane,      wc * g0 * y12);
    atomicAdd(ar + 128 +   0 + 64 + lane, wd * g10 * y0);
    atomicAdd(ar + 128 + 128 + 64 + lane, wd * g11 * y0);
    atomicAdd(ar + 128 + 256 + 64 + lane, wd * g12 * y0);
}

__global__ __launch_bounds__(256) void k_node_out_legacy(
    const float* __restrict__ acc, const float* __restrict__ attr,
    const float* __restrict__ deg, const float* __restrict__ Wlo0,
    const float* __restrict__ Wlo1, float* __restrict__ out)
{
    __shared__ float sm[4][512];
    const int wave = threadIdx.x >> 6;
    const int lane = threadIdx.x & 63;
    const int n = blockIdx.x * 4 + wave;

    const float dis = 1.0f / sqrtf(deg[n]);
    const float* ar = acc + (size_t)n * 512;
    for (int i = lane; i < 512; i += 64) sm[wave][i] = ar[i] * dis;
    __syncthreads();

    float o0 = 0.f, o1x = 0.f, o1y = 0.f, o1z = 0.f;
    for (int c = 0; c < 128; ++c) {
        float w0 = Wlo0[c*64 + lane];
        float w1 = Wlo1[c*64 + lane];
        o0  += sm[wave][c]        * w0;
        o1x += sm[wave][128 + c]  * w1;
        o1y += sm[wave][256 + c]  * w1;
        o1z += sm[wave][384 + c]  * w1;
    }

    const float a = attr[n] * INVLO;
    float* orow = out + (size_t)n * 256;
    orow[lane] += C_X * o0 * a;
    orow[64 + lane*3    ] += C_X * o1x * a;
    orow[64 + lane*3 + 1] += C_X * o1y * a;
    orow[64 + lane*3 + 2] += C_X * o1z * a;
}

// ============================================================================
extern "C" void kernel_launch(void* const* d_in, const int* in_sizes, int n_in,
                              void* d_out, int out_size, void* d_ws, size_t ws_size,
                              hipStream_t stream) {
    const float* ni    = (const float*)d_in[0];
    const float* attr  = (const float*)d_in[1];
    const float* deg   = (const float*)d_in[2];
    const float* eattr = (const float*)d_in[3];
    const float* elen  = (const float*)d_in[4];
    const float* Wli0  = (const float*)d_in[5];
    const float* Wli1  = (const float*)d_in[6];
    const float* Wlm0  = (const float*)d_in[7];
    const float* Wlm1  = (const float*)d_in[8];
    const float* Wm1   = (const float*)d_in[9];
    const float* Wm2   = (const float*)d_in[10];
    const float* Wlo0  = (const float*)d_in[11];
    const float* Wlo1  = (const float*)d_in[12];
    const int*   esrc  = (const int*)d_in[13];
    const int*   edst  = (const int*)d_in[14];

    float* out = (float*)d_out;

    // ws layout (fast path), 16B-aligned sections
    char* wsb = (char*)d_ws;
    size_t off = 0;
    float4* fv = (float4*)(wsb + off);            off += (size_t)N_NODES * 64 * 16;      // 20.48 MB
    __hip_bfloat16* ew = (__hip_bfloat16*)(wsb + off); off += (size_t)N_EDGES * 256 * 2; // 163.84 MB
    float4* eattrs = (float4*)(wsb + off);        off += (size_t)N_EDGES * 16;           // 5.12 MB
    int* esrc_s = (int*)(wsb + off);              off += (size_t)N_EDGES * 4;            // 1.28 MB
    int* perm   = (int*)(wsb + off);              off += (size_t)N_EDGES * 4;            // 1.28 MB
    unsigned short* w2t = (unsigned short*)(wsb + off); off += 32768 * 2;                // 64 KB
    int* starts = (int*)(wsb + off);              off += (size_t)(N_NODES + 4) * 4;
    int* hist   = (int*)(wsb + off);              off += (size_t)N_NODES * 4;
    int* cursor = (int*)(wsb + off);              off += (size_t)N_NODES * 4;
    const size_t need_fast = off;

    if (ws_size >= need_fast) {
        hipMemsetAsync(hist, 0, (size_t)N_NODES * sizeof(int), stream);
        k_node_in<<<N_NODES / 4, 256, 0, stream>>>(ni, attr, deg, Wli0, Wli1,
                                                   Wlm0, Wlm1, fv, out);
        k_w2t    <<<128, 256, 0, stream>>>(Wm2, w2t);
        k_hist   <<<N_EDGES / 256, 256, 0, stream>>>(edst, hist);
        k_scan   <<<1, 1024, 0, stream>>>(hist, starts, cursor);
        k_scatter<<<N_EDGES / 256, 256, 0, stream>>>(esrc, edst,
                                                     (const float4*)eattr,
                                                     cursor, perm, esrc_s, eattrs);
        k_mlp    <<<N_EDGES / 128, 256, 0, stream>>>(elen, Wm1, w2t, perm, ew);
        k_gather <<<N_NODES / 4, 256, 0, stream>>>(starts, esrc_s, eattrs, ew,
                                                   fv, attr, deg, Wlo0, Wlo1, out);
    } else {
        // fallback: round-1 atomic path (61.4 MB scratch)
        float* f   = (float*)d_ws;
        float* acc = f + (size_t)N_NODES * 256;
        hipMemsetAsync(acc, 0, (size_t)N_NODES * 512 * sizeof(float), stream);
        k_node_in_legacy<<<N_NODES / 4, 256, 0, stream>>>(ni, attr, deg, Wli0, Wli1,
                                                          Wlm0, Wlm1, f, out);
        k_edge_legacy<<<N_EDGES / 4, 256, 0, stream>>>(eattr, elen, Wm1, Wm2,
                                                       esrc, edst, f, acc);
        k_node_out_legacy<<<N_NODES / 4, 256, 0, stream>>>(acc, attr, deg,
                                                           Wlo0, Wlo1, out);
    }
}

// Round 4
// 414.061 us; speedup vs baseline: 3.0680x; 1.1197x over previous
//
#include <hip/hip_runtime.h>
#include <hip/hip_bf16.h>
#include <math.h>

#define N_NODES 20000
#define N_EDGES 320000

#define INV1   0.31622776601683794f   // 1/sqrt(10)
#define SC2    0.1f                   // 1/sqrt(100)
#define IS3    0.5773502691896258f    // 1/sqrt(3)
#define C_S    0.3826834323650898f    // sin(pi/8)
#define C_X    0.9238795325112867f    // cos(pi/8)
#define INV64  0.125f                 // 1/sqrt(64)
#define INVLO  0.08838834764831845f   // 1/sqrt(128)

typedef short     short8 __attribute__((ext_vector_type(8)));
typedef float     f32x4  __attribute__((ext_vector_type(4)));

__device__ __forceinline__ float silu_f(float x) {
    return x / (1.0f + expf(-x));
}
__device__ __forceinline__ unsigned short f2bf(float x) {
    __hip_bfloat16 h = __float2bfloat16(x);
    return *reinterpret_cast<unsigned short*>(&h);
}
__device__ __forceinline__ float bf2f(unsigned short u) {
    __hip_bfloat16 h;
    *reinterpret_cast<unsigned short*>(&h) = u;
    return __bfloat162float(h);
}

// ---------------- node pre-pass: fvb[n][64] = ushort4 bf16, out = c_s * m ---
__global__ __launch_bounds__(256) void k_node_in(
    const float* __restrict__ ni, const float* __restrict__ attr,
    const float* __restrict__ deg,
    const float* __restrict__ Wli0, const float* __restrict__ Wli1,
    const float* __restrict__ Wlm0, const float* __restrict__ Wlm1,
    ushort4* __restrict__ fvb, float* __restrict__ out)
{
    __shared__ float raw[4][256];
    const int wave = threadIdx.x >> 6;
    const int lane = threadIdx.x & 63;
    const int n = blockIdx.x * 4 + wave;

    const float* row = ni + (size_t)n * 256;
    raw[wave][lane      ] = row[lane      ];
    raw[wave][lane + 64 ] = row[lane + 64 ];
    raw[wave][lane + 128] = row[lane + 128];
    raw[wave][lane + 192] = row[lane + 192];
    __syncthreads();

    float f0 = 0.f, m0 = 0.f;
    float f1x = 0.f, f1y = 0.f, f1z = 0.f;
    float m1x = 0.f, m1y = 0.f, m1z = 0.f;
    #pragma unroll 4
    for (int t = 0; t < 64; ++t) {
        float xs  = raw[wave][t];
        float xv0 = raw[wave][64 + t*3    ];
        float xv1 = raw[wave][64 + t*3 + 1];
        float xv2 = raw[wave][64 + t*3 + 2];
        float a0 = Wli0[t*64 + lane];
        float a1 = Wli1[t*64 + lane];
        float b0 = Wlm0[t*64 + lane];
        float b1 = Wlm1[t*64 + lane];
        f0  += xs  * a0;   m0  += xs  * b0;
        f1x += xv0 * a1;   f1y += xv1 * a1;   f1z += xv2 * a1;
        m1x += xv0 * b1;   m1y += xv1 * b1;   m1z += xv2 * b1;
    }

    const float a   = attr[n] * INV64;
    const float dis = 1.0f / sqrtf(deg[n]);
    const float fa  = a * dis;

    ushort4 pk;
    pk.x = f2bf(f0  * fa);
    pk.y = f2bf(f1x * fa);
    pk.z = f2bf(f1y * fa);
    pk.w = f2bf(f1z * fa);
    fvb[(size_t)n * 64 + lane] = pk;

    float* orow = out + (size_t)n * 256;
    orow[lane] = C_S * m0 * a;
    orow[64 + lane*3    ] = C_S * m1x * a;
    orow[64 + lane*3 + 1] = C_S * m1y * a;
    orow[64 + lane*3 + 2] = C_S * m1z * a;
}

// ---------------- weight prep: w2t[256][128], w1t[112][32] (bf16, scaled) ---
__global__ __launch_bounds__(256) void k_w2t(
    const float* __restrict__ W2, const float* __restrict__ W1,
    unsigned short* __restrict__ w2t, unsigned short* __restrict__ w1t)
{
    const int i = blockIdx.x * 256 + threadIdx.x;
    if (i < 32768) {
        const int n = i >> 7, k = i & 127;
        w2t[i] = (k < 100) ? f2bf(W2[k*256 + n] * SC2) : (unsigned short)0;
    } else if (i < 32768 + 3584) {
        const int j = i - 32768;
        const int n = j >> 5, k = j & 31;
        w1t[j] = (k < 10 && n < 100) ? f2bf(W1[k*100 + n] * INV1)
                                     : (unsigned short)0;
    }
}

// ---------------- counting sort by dst + sorted edge data -------------------
__global__ __launch_bounds__(256) void k_hist(const int* __restrict__ edst,
                                              int* __restrict__ hist) {
    const int e = blockIdx.x * 256 + threadIdx.x;
    if (e < N_EDGES) atomicAdd(&hist[edst[e]], 1);
}

__global__ __launch_bounds__(1024) void k_scan(const int* __restrict__ hist,
                                               int* __restrict__ starts,
                                               int* __restrict__ cursor) {
    __shared__ int part[1024];
    const int t = threadIdx.x;
    const int C = 20;
    const int base = t * C;
    int s = 0;
    for (int i = 0; i < C; ++i) {
        const int idx = base + i;
        if (idx < N_NODES) s += hist[idx];
    }
    part[t] = s;
    __syncthreads();
    for (int off = 1; off < 1024; off <<= 1) {
        int v = (t >= off) ? part[t - off] : 0;
        __syncthreads();
        part[t] += v;
        __syncthreads();
    }
    int run = part[t] - s;
    for (int i = 0; i < C; ++i) {
        const int idx = base + i;
        if (idx < N_NODES) {
            starts[idx] = run;
            cursor[idx] = run;
            run += hist[idx];
        }
    }
    if (t == 1023) starts[N_NODES] = N_EDGES;
}

__global__ __launch_bounds__(256) void k_scatter(
    const int* __restrict__ esrc, const int* __restrict__ edst,
    const float4* __restrict__ eattr4, const float* __restrict__ elen,
    int* __restrict__ cursor, int* __restrict__ esrc_s,
    float4* __restrict__ eattrs, unsigned short* __restrict__ elen_sb)
{
    const int e = blockIdx.x * 256 + threadIdx.x;
    if (e < N_EDGES) {
        const int p = atomicAdd(&cursor[edst[e]], 1);
        esrc_s[p] = esrc[e];
        eattrs[p] = eattr4[e];
        const float* el = elen + (size_t)e * 10;
        unsigned short v[32];
        #pragma unroll
        for (int b = 0; b < 10; ++b) v[b] = f2bf(el[b]);
        #pragma unroll
        for (int b = 10; b < 32; ++b) v[b] = 0;
        short8* dst = (short8*)(elen_sb + (size_t)p * 32);
        #pragma unroll
        for (int s = 0; s < 4; ++s) {
            short8 pk;
            #pragma unroll
            for (int j = 0; j < 8; ++j) pk[j] = (short)v[s*8 + j];
            dst[s] = pk;
        }
    }
}

// ---------------- edge MLP, MFMA, sorted in/out, barrier-free ---------------
// 128 edges/block (sorted positions), 32/wave. LDS = Hs only (34.8 KB -> 4 blk/CU).
__global__ __launch_bounds__(256, 4) void k_mlp(
    const unsigned short* __restrict__ elen_sb,
    const unsigned short* __restrict__ w1t,
    const unsigned short* __restrict__ w2t,
    unsigned short* __restrict__ ew)
{
    __shared__ unsigned short Hs[128 * 136];   // [e][k] stride 136 (272 B, 16-al)
    const int t    = threadIdx.x;
    const int w    = t >> 6;
    const int lane = t & 63;
    const int m15  = lane & 15;
    const int q    = lane >> 4;
    const int eb   = w * 32;
    const int e0   = blockIdx.x * 128;

    // zero own wave's pad cols 112..127 (cols 100..111 become silu(0)=0 via w1t)
    {
        const int r = eb + (lane >> 1);
        const int c = 112 + (lane & 1) * 8;
        short8 z = {0,0,0,0,0,0,0,0};
        *(short8*)&Hs[r*136 + c] = z;
    }

    // A-frags for H GEMM: one 16 B load each (sorted, padded bf16 X)
    short8 xa0 = *(const short8*)(elen_sb + (size_t)(e0 + eb      + m15)*32 + q*8);
    short8 xa1 = *(const short8*)(elen_sb + (size_t)(e0 + eb + 16 + m15)*32 + q*8);

    // ---- H GEMM: K=32 (padded), 7 n-tiles; INV1 folded into w1t ----
    for (int nt = 0; nt < 7; ++nt) {
        short8 bw = *(const short8*)(w1t + (nt*16 + m15)*32 + q*8);
        f32x4 z4 = {0.f, 0.f, 0.f, 0.f};
        f32x4 h0 = __builtin_amdgcn_mfma_f32_16x16x32_bf16(xa0, bw, z4, 0, 0, 0);
        f32x4 h1 = __builtin_amdgcn_mfma_f32_16x16x32_bf16(xa1, bw, z4, 0, 0, 0);
        #pragma unroll
        for (int r = 0; r < 4; ++r) {
            Hs[(eb      + q*4 + r)*136 + nt*16 + m15] = f2bf(silu_f(h0[r]));
            Hs[(eb + 16 + q*4 + r)*136 + nt*16 + m15] = f2bf(silu_f(h1[r]));
        }
    }
    // same-wave RAW on Hs -> compiler lgkmcnt, no barrier

    short8 A0[4], A1[4];
    #pragma unroll
    for (int s = 0; s < 4; ++s) {
        A0[s] = *(const short8*)&Hs[(eb      + m15)*136 + s*32 + q*8];
        A1[s] = *(const short8*)&Hs[(eb + 16 + m15)*136 + s*32 + q*8];
    }

    // ---- big GEMM: SC2 folded into w2t; stage C in own Hs region, copy out
    unsigned short* stg = &Hs[eb * 136];       // 32 rows x 136, per-wave
    #pragma unroll
    for (int half = 0; half < 2; ++half) {
        for (int nt8 = 0; nt8 < 8; ++nt8) {
            const int nt = half*8 + nt8;
            f32x4 c0 = {0.f,0.f,0.f,0.f}, c1 = {0.f,0.f,0.f,0.f};
            const unsigned short* bp = w2t + ((size_t)(nt*16 + m15) << 7);
            #pragma unroll
            for (int s = 0; s < 4; ++s) {
                short8 B = *(const short8*)(bp + s*32 + q*8);
                c0 = __builtin_amdgcn_mfma_f32_16x16x32_bf16(A0[s], B, c0, 0, 0, 0);
                c1 = __builtin_amdgcn_mfma_f32_16x16x32_bf16(A1[s], B, c1, 0, 0, 0);
            }
            #pragma unroll
            for (int r = 0; r < 4; ++r) {
                stg[(     q*4 + r)*136 + nt8*16 + m15] = f2bf(c0[r]);
                stg[(16 + q*4 + r)*136 + nt8*16 + m15] = f2bf(c1[r]);
            }
        }
        // coalesced copy-out: 8 KB -> global (rows contiguous, sorted)
        unsigned short* gb = ew + (size_t)(e0 + eb) * 256 + half * 128;
        #pragma unroll
        for (int i = 0; i < 8; ++i) {
            const int p   = i*1024 + lane*16;   // byte offset in 8 KB tile
            const int row = p >> 8;
            const int wi  = p & 255;            // bytes within 256 B row-half
            short8 v = *(const short8*)((const char*)stg + row*272 + wi);
            *(short8*)((char*)(gb + (size_t)row*256) + wi) = v;
        }
    }
}

// ---------------- per-dst gather + fused W_lo GEMM + epilogue ---------------
__global__ __launch_bounds__(256) void k_gather(
    const int* __restrict__ starts, const int* __restrict__ esrc_s,
    const float4* __restrict__ eattrs, const unsigned short* __restrict__ ew,
    const ushort4* __restrict__ fvb,
    const float* __restrict__ attr, const float* __restrict__ deg,
    const float* __restrict__ Wlo0, const float* __restrict__ Wlo1,
    float* __restrict__ out)
{
    __shared__ float sm[4][512];
    const int wave = threadIdx.x >> 6;
    const int lane = threadIdx.x & 63;
    const int n = blockIdx.x * 4 + wave;

    const int beg = starts[n], end = starts[n + 1];
    float sA=0.f, sB=0.f;
    float vA0=0.f, vA1=0.f, vA2=0.f;
    float vB0=0.f, vB1=0.f, vB2=0.f;

    for (int base = beg; base < end; base += 64) {
        const int cnt = min(64, end - base);
        int    srcv = 0;
        float4 eav  = make_float4(0.f, 0.f, 0.f, 0.f);
        if (lane < cnt) {
            srcv = esrc_s[base + lane];
            eav  = eattrs[base + lane];
        }
        #pragma unroll 2
        for (int j = 0; j < cnt; ++j) {
            const int   src = __shfl(srcv, j);
            const float y0  = __shfl(eav.x, j);
            const float y10 = __shfl(eav.y, j);
            const float y11 = __shfl(eav.z, j);
            const float y12 = __shfl(eav.w, j);

            const unsigned short* wr = ew + (size_t)(base + j) * 256;
            const float wa = bf2f(wr[lane      ]);
            const float wb = bf2f(wr[64  + lane]);
            const float wc = bf2f(wr[128 + lane]);
            const float wd = bf2f(wr[192 + lane]);

            const ushort4 g4 = fvb[(size_t)src * 64 + lane];
            const float g0  = bf2f(g4.x);
            const float g10 = bf2f(g4.y);
            const float g11 = bf2f(g4.z);
            const float g12 = bf2f(g4.w);

            const float dotv = g10*y10 + g11*y11 + g12*y12;
            sA += wa * g0 * y0;
            sB += wb * dotv;
            const float t0 = wc * g0;
            vA0 += t0 * y10;  vA1 += t0 * y11;  vA2 += t0 * y12;
            const float t1 = wd * y0;
            vB0 += t1 * g10;  vB1 += t1 * g11;  vB2 += t1 * g12;
        }
    }

    const float dis = 1.0f / sqrtf(deg[n]);
    sm[wave][lane            ] = sA * dis;
    sm[wave][64  + lane      ] = sB * IS3 * dis;
    sm[wave][128 + lane      ] = vA0 * dis;
    sm[wave][128 + 64 + lane ] = vB0 * dis;
    sm[wave][256 + lane      ] = vA1 * dis;
    sm[wave][256 + 64 + lane ] = vB1 * dis;
    sm[wave][384 + lane      ] = vA2 * dis;
    sm[wave][384 + 64 + lane ] = vB2 * dis;
    __syncthreads();

    float o0=0.f, o1x=0.f, o1y=0.f, o1z=0.f;
    #pragma unroll 4
    for (int c = 0; c < 128; ++c) {
        const float w0 = Wlo0[c*64 + lane];
        const float w1 = Wlo1[c*64 + lane];
        o0  += sm[wave][c]         * w0;
        o1x += sm[wave][128 + c]   * w1;
        o1y += sm[wave][256 + c]   * w1;
        o1z += sm[wave][384 + c]   * w1;
    }

    const float a = attr[n] * INVLO;
    float* orow = out + (size_t)n * 256;
    orow[lane] += C_X * o0 * a;
    orow[64 + lane*3    ] += C_X * o1x * a;
    orow[64 + lane*3 + 1] += C_X * o1y * a;
    orow[64 + lane*3 + 2] += C_X * o1z * a;
}

// ======================= fallback (round-1) path ============================
__global__ __launch_bounds__(256) void k_node_in_legacy(
    const float* __restrict__ ni, const float* __restrict__ attr,
    const float* __restrict__ deg,
    const float* __restrict__ Wli0, const float* __restrict__ Wli1,
    const float* __restrict__ Wlm0, const float* __restrict__ Wlm1,
    float* __restrict__ f, float* __restrict__ out)
{
    __shared__ float raw[4][256];
    const int wave = threadIdx.x >> 6;
    const int lane = threadIdx.x & 63;
    const int n = blockIdx.x * 4 + wave;

    const float* row = ni + (size_t)n * 256;
    raw[wave][lane      ] = row[lane      ];
    raw[wave][lane + 64 ] = row[lane + 64 ];
    raw[wave][lane + 128] = row[lane + 128];
    raw[wave][lane + 192] = row[lane + 192];
    __syncthreads();

    float f0 = 0.f, m0 = 0.f;
    float f1x = 0.f, f1y = 0.f, f1z = 0.f;
    float m1x = 0.f, m1y = 0.f, m1z = 0.f;
    for (int t = 0; t < 64; ++t) {
        float xs  = raw[wave][t];
        float xv0 = raw[wave][64 + t*3    ];
        float xv1 = raw[wave][64 + t*3 + 1];
        float xv2 = raw[wave][64 + t*3 + 2];
        float a0 = Wli0[t*64 + lane];
        float a1 = Wli1[t*64 + lane];
        float b0 = Wlm0[t*64 + lane];
        float b1 = Wlm1[t*64 + lane];
        f0  += xs  * a0;   m0  += xs  * b0;
        f1x += xv0 * a1;   f1y += xv1 * a1;   f1z += xv2 * a1;
        m1x += xv0 * b1;   m1y += xv1 * b1;   m1z += xv2 * b1;
    }

    const float a   = attr[n] * INV64;
    const float dis = 1.0f / sqrtf(deg[n]);
    const float fa  = a * dis;

    float* fr = f + (size_t)n * 256;
    fr[lane      ] = f0  * fa;
    fr[64  + lane] = f1x * fa;
    fr[128 + lane] = f1y * fa;
    fr[192 + lane] = f1z * fa;

    float* orow = out + (size_t)n * 256;
    orow[lane] = C_S * m0 * a;
    orow[64 + lane*3    ] = C_S * m1x * a;
    orow[64 + lane*3 + 1] = C_S * m1y * a;
    orow[64 + lane*3 + 2] = C_S * m1z * a;
}

__global__ __launch_bounds__(256) void k_edge_legacy(
    const float* __restrict__ eattr, const float* __restrict__ elen,
    const float* __restrict__ W1, const float* __restrict__ W2,
    const int* __restrict__ esrc, const int* __restrict__ edst,
    const float* __restrict__ f, float* __restrict__ acc)
{
    __shared__ float hsh[4][104];
    const int wave = threadIdx.x >> 6;
    const int lane = threadIdx.x & 63;
    const int e = blockIdx.x * 4 + wave;

    const float* el = elen + (size_t)e * 10;
    float elr[10];
    #pragma unroll
    for (int b = 0; b < 10; ++b) elr[b] = el[b];

    float a1 = 0.f;
    #pragma unroll
    for (int b = 0; b < 10; ++b) a1 += elr[b] * W1[b*100 + lane];
    hsh[wave][lane] = silu_f(a1 * INV1);
    if (lane < 36) {
        float a2 = 0.f;
        #pragma unroll
        for (int b = 0; b < 10; ++b) a2 += elr[b] * W1[b*100 + 64 + lane];
        hsh[wave][64 + lane] = silu_f(a2 * INV1);
    }
    __syncthreads();

    float wa = 0.f, wb = 0.f, wc = 0.f, wd = 0.f;
    for (int j = 0; j < 100; ++j) {
        float hj = hsh[wave][j];
        const float* wr = W2 + j*256;
        wa += hj * wr[lane      ];
        wb += hj * wr[64  + lane];
        wc += hj * wr[128 + lane];
        wd += hj * wr[192 + lane];
    }
    wa *= SC2; wb *= SC2; wc *= SC2; wd *= SC2;

    const int src = esrc[e];
    const int dst = edst[e];
    const float y0  = eattr[e*4 + 0];
    const float y10 = eattr[e*4 + 1];
    const float y11 = eattr[e*4 + 2];
    const float y12 = eattr[e*4 + 3];

    const float* fr = f + (size_t)src * 256;
    const float g0  = fr[lane      ];
    const float g10 = fr[64  + lane];
    const float g11 = fr[128 + lane];
    const float g12 = fr[192 + lane];

    const float dotv = g10*y10 + g11*y11 + g12*y12;

    float* ar = acc + (size_t)dst * 512;
    atomicAdd(ar + lane,                  wa * g0 * y0);
    atomicAdd(ar + 64 + lane,             wb * dotv * IS3);
    atomicAdd(ar + 128 +   0 + lane,      wc * g0 * y10);
    atomicAdd(ar + 128 + 128 + lane,      wc * g0 * y11);
    atomicAdd(ar + 128 + 256 + lane,      wc * g0 * y12);
    atomicAdd(ar + 128 +   0 + 64 + lane, wd * g10 * y0);
    atomicAdd(ar + 128 + 128 + 64 + lane, wd * g11 * y0);
    atomicAdd(ar + 128 + 256 + 64 + lane, wd * g12 * y0);
}

__global__ __launch_bounds__(256) void k_node_out_legacy(
    const float* __restrict__ acc, const float* __restrict__ attr,
    const float* __restrict__ deg, const float* __restrict__ Wlo0,
    const float* __restrict__ Wlo1, float* __restrict__ out)
{
    __shared__ float sm[4][512];
    const int wave = threadIdx.x >> 6;
    const int lane = threadIdx.x & 63;
    const int n = blockIdx.x * 4 + wave;

    const float dis = 1.0f / sqrtf(deg[n]);
    const float* ar = acc + (size_t)n * 512;
    for (int i = lane; i < 512; i += 64) sm[wave][i] = ar[i] * dis;
    __syncthreads();

    float o0 = 0.f, o1x = 0.f, o1y = 0.f, o1z = 0.f;
    for (int c = 0; c < 128; ++c) {
        float w0 = Wlo0[c*64 + lane];
        float w1 = Wlo1[c*64 + lane];
        o0  += sm[wave][c]        * w0;
        o1x += sm[wave][128 + c]  * w1;
        o1y += sm[wave][256 + c]  * w1;
        o1z += sm[wave][384 + c]  * w1;
    }

    const float a = attr[n] * INVLO;
    float* orow = out + (size_t)n * 256;
    orow[lane] += C_X * o0 * a;
    orow[64 + lane*3    ] += C_X * o1x * a;
    orow[64 + lane*3 + 1] += C_X * o1y * a;
    orow[64 + lane*3 + 2] += C_X * o1z * a;
}

// ============================================================================
extern "C" void kernel_launch(void* const* d_in, const int* in_sizes, int n_in,
                              void* d_out, int out_size, void* d_ws, size_t ws_size,
                              hipStream_t stream) {
    const float* ni    = (const float*)d_in[0];
    const float* attr  = (const float*)d_in[1];
    const float* deg   = (const float*)d_in[2];
    const float* eattr = (const float*)d_in[3];
    const float* elen  = (const float*)d_in[4];
    const float* Wli0  = (const float*)d_in[5];
    const float* Wli1  = (const float*)d_in[6];
    const float* Wlm0  = (const float*)d_in[7];
    const float* Wlm1  = (const float*)d_in[8];
    const float* Wm1   = (const float*)d_in[9];
    const float* Wm2   = (const float*)d_in[10];
    const float* Wlo0  = (const float*)d_in[11];
    const float* Wlo1  = (const float*)d_in[12];
    const int*   esrc  = (const int*)d_in[13];
    const int*   edst  = (const int*)d_in[14];

    float* out = (float*)d_out;

    // ws layout (fast path), 16 B-aligned sections
    char* wsb = (char*)d_ws;
    size_t off = 0;
    ushort4* fvb = (ushort4*)(wsb + off);               off += (size_t)N_NODES * 64 * 8;    // 10.24 MB
    unsigned short* ew = (unsigned short*)(wsb + off);  off += (size_t)N_EDGES * 256 * 2;   // 163.84 MB
    unsigned short* elen_sb = (unsigned short*)(wsb + off); off += (size_t)N_EDGES * 32 * 2;// 20.48 MB
    float4* eattrs = (float4*)(wsb + off);              off += (size_t)N_EDGES * 16;        // 5.12 MB
    int* esrc_s = (int*)(wsb + off);                    off += (size_t)N_EDGES * 4;         // 1.28 MB
    unsigned short* w2t = (unsigned short*)(wsb + off); off += 32768 * 2;
    unsigned short* w1t = (unsigned short*)(wsb + off); off += 3584 * 2;
    int* starts = (int*)(wsb + off);                    off += (size_t)(N_NODES + 4) * 4;
    int* hist   = (int*)(wsb + off);                    off += (size_t)N_NODES * 4;
    int* cursor = (int*)(wsb + off);                    off += (size_t)N_NODES * 4;
    const size_t need_fast = off;

    if (ws_size >= need_fast) {
        hipMemsetAsync(hist, 0, (size_t)N_NODES * sizeof(int), stream);
        k_node_in<<<N_NODES / 4, 256, 0, stream>>>(ni, attr, deg, Wli0, Wli1,
                                                   Wlm0, Wlm1, fvb, out);
        k_w2t    <<<144, 256, 0, stream>>>(Wm2, Wm1, w2t, w1t);
        k_hist   <<<N_EDGES / 256, 256, 0, stream>>>(edst, hist);
        k_scan   <<<1, 1024, 0, stream>>>(hist, starts, cursor);
        k_scatter<<<N_EDGES / 256, 256, 0, stream>>>(esrc, edst,
                                                     (const float4*)eattr, elen,
                                                     cursor, esrc_s, eattrs, elen_sb);
        k_mlp    <<<N_EDGES / 128, 256, 0, stream>>>(elen_sb, w1t, w2t, ew);
        k_gather <<<N_NODES / 4, 256, 0, stream>>>(starts, esrc_s, eattrs, ew,
                                                   fvb, attr, deg, Wlo0, Wlo1, out);
    } else {
        // fallback: round-1 atomic path (61.4 MB scratch)
        float* f   = (float*)d_ws;
        float* acc = f + (size_t)N_NODES * 256;
        hipMemsetAsync(acc, 0, (size_t)N_NODES * 512 * sizeof(float), stream);
        k_node_in_legacy<<<N_NODES / 4, 256, 0, stream>>>(ni, attr, deg, Wli0, Wli1,
                                                          Wlm0, Wlm1, f, out);
        k_edge_legacy<<<N_EDGES / 4, 256, 0, stream>>>(eattr, elen, Wm1, Wm2,
                                                       esrc, edst, f, acc);
        k_node_out_legacy<<<N_NODES / 4, 256, 0, stream>>>(acc, attr, deg,
                                                           Wlo0, Wlo1, out);
    }
}